// Round 1
// baseline (277.585 us; speedup 1.0000x reference)
//
#include <hip/hip_runtime.h>
#include <math.h>

// Problem constants (fixed by setup_inputs)
#define Nn 4
#define Ll 4096
#define Ss 256
#define Cc 256
#define Hh 256
#define FC 8
#define SC 32     // Hh/FC
#define TM 16     // rows per block in the row-GEMM kernels

// ---------------------------------------------------------------------------
// Kernel A: c1 = center1 @ W1^T + b1 ; split into c_point (l2-normalized) and
// c_value. Layout out: cpn[n][f][s][32], cval[n][f][s][32].
// Block = 256 threads handles (n, 16 s-rows); thread t computes cols t, t+256.
// ---------------------------------------------------------------------------
__global__ __launch_bounds__(256) void c1_kernel(
    const float* __restrict__ center1, const float* __restrict__ W1,
    const float* __restrict__ b1, float* __restrict__ cpn,
    float* __restrict__ cval) {
  __shared__ float cs[16][Cc];       // 16 KB: center rows
  __shared__ float os[16][2 * Hh];   // 32 KB: outputs
  __shared__ float nr[16][FC];
  int t = threadIdx.x;
  int nI = blockIdx.x / (Ss / 16);
  int s0 = (blockIdx.x % (Ss / 16)) * 16;

  const float4* src = (const float4*)(center1 + ((size_t)nI * Ss + s0) * Cc);
  float4* dst = (float4*)&cs[0][0];
  for (int i = t; i < 16 * Cc / 4; i += 256) dst[i] = src[i];
  __syncthreads();

  float acc0[16], acc1[16];
  int c0 = t, c1 = t + 256;
  float b00 = b1[c0], b01 = b1[c1];
#pragma unroll
  for (int r = 0; r < 16; r++) { acc0[r] = b00; acc1[r] = b01; }

  const float4* w0 = (const float4*)(W1 + (size_t)c0 * Cc);
  const float4* w1 = (const float4*)(W1 + (size_t)c1 * Cc);
  for (int k4 = 0; k4 < Cc / 4; k4++) {
    float4 wa = w0[k4], wb = w1[k4];
#pragma unroll
    for (int r = 0; r < 16; r++) {
      float4 xv = *(const float4*)&cs[r][k4 * 4];
      acc0[r] = fmaf(xv.x, wa.x, acc0[r]); acc0[r] = fmaf(xv.y, wa.y, acc0[r]);
      acc0[r] = fmaf(xv.z, wa.z, acc0[r]); acc0[r] = fmaf(xv.w, wa.w, acc0[r]);
      acc1[r] = fmaf(xv.x, wb.x, acc1[r]); acc1[r] = fmaf(xv.y, wb.y, acc1[r]);
      acc1[r] = fmaf(xv.z, wb.z, acc1[r]); acc1[r] = fmaf(xv.w, wb.w, acc1[r]);
    }
  }
#pragma unroll
  for (int r = 0; r < 16; r++) { os[r][c0] = acc0[r]; os[r][c1] = acc1[r]; }
  __syncthreads();

  if (t < 128) {  // 16 rows x 8 fibers
    int r = t >> 3, f = t & 7;
    float ss = 0.f;
#pragma unroll
    for (int j = 0; j < SC; j++) { float v = os[r][f * 64 + j]; ss += v * v; }
    nr[r][f] = fmaxf(sqrtf(ss), 1e-12f);
  }
  __syncthreads();

#pragma unroll
  for (int cc = 0; cc < 2; cc++) {
    int c = t + cc * 256;
    int f = c >> 6, q = c & 63;
    for (int r = 0; r < 16; r++) {
      float v = os[r][c];
      size_t base = (((size_t)nI * FC + f) * Ss + (size_t)(s0 + r)) * SC;
      if (q < SC) cpn[base + q] = v / nr[r][f];
      else        cval[base + (q - SC)] = v;
    }
  }
}

// ---------------------------------------------------------------------------
// Kernel B: x0p = x0 @ W0^T + b0, then l2norm per 32-channel fiber chunk.
// Output xn[n][l][256] (channel = f*32+j). Block = 16 rows, thread = 1 column.
// ---------------------------------------------------------------------------
__global__ __launch_bounds__(256) void x0p_kernel(
    const float* __restrict__ x0, const float* __restrict__ W0,
    const float* __restrict__ b0, float* __restrict__ xn) {
  __shared__ float xs[TM][Cc];   // 16 KB
  __shared__ float os[TM][Cc];   // 16 KB
  __shared__ float nr[TM][FC];
  int t = threadIdx.x;
  size_t row0 = (size_t)blockIdx.x * TM;

  const float4* src = (const float4*)(x0 + row0 * Cc);
  float4* dst = (float4*)&xs[0][0];
  for (int i = t; i < TM * Cc / 4; i += 256) dst[i] = src[i];
  __syncthreads();

  float acc[TM];
  float bb = b0[t];
#pragma unroll
  for (int r = 0; r < TM; r++) acc[r] = bb;

  const float4* w4 = (const float4*)(W0 + (size_t)t * Cc);
  for (int k4 = 0; k4 < Cc / 4; k4++) {
    float4 wv = w4[k4];
#pragma unroll
    for (int r = 0; r < TM; r++) {
      float4 xv = *(const float4*)&xs[r][k4 * 4];
      acc[r] = fmaf(xv.x, wv.x, acc[r]); acc[r] = fmaf(xv.y, wv.y, acc[r]);
      acc[r] = fmaf(xv.z, wv.z, acc[r]); acc[r] = fmaf(xv.w, wv.w, acc[r]);
    }
  }
#pragma unroll
  for (int r = 0; r < TM; r++) os[r][t] = acc[r];
  __syncthreads();

  if (t < TM * FC) {  // 128 norm groups
    int r = t >> 3, f = t & 7;
    float ss = 0.f;
#pragma unroll
    for (int j = 0; j < SC; j++) { float v = os[r][f * SC + j]; ss += v * v; }
    nr[r][f] = fmaxf(sqrtf(ss), 1e-12f);
  }
  __syncthreads();

  int f = t >> 5;
#pragma unroll
  for (int r = 0; r < TM; r++)
    xn[(row0 + r) * Cc + t] = os[r][t] / nr[r][f];
}

// ---------------------------------------------------------------------------
// Kernel C: per (n, f, l): sim against 256 centers (c_point in LDS, broadcast
// reads), running max/argmax of t = alpha*sim+beta (sigmoid is monotone),
// gather c_value[argmax], scale by sigmoid(max), write dispatched row chunk
// into d_out ([n][l][H], channels f*32..f*32+31). 2 l-rows per thread.
// ---------------------------------------------------------------------------
__global__ __launch_bounds__(256) void sim_kernel(
    const float* __restrict__ xn, const float* __restrict__ cpn,
    const float* __restrict__ cval, const float* __restrict__ alphap,
    const float* __restrict__ betap, float* __restrict__ disp) {
  __shared__ float cs[Ss * SC];  // 32 KB
  int t = threadIdx.x;
  int lt = blockIdx.x & 7;          // l-tile (8 tiles of 512)
  int f  = (blockIdx.x >> 3) & 7;   // fiber
  int nI = blockIdx.x >> 6;         // batch

  const float4* cp4 = (const float4*)(cpn + ((size_t)nI * FC + f) * Ss * SC);
  float4* cs4 = (float4*)cs;
  for (int i = t; i < Ss * SC / 4; i += 256) cs4[i] = cp4[i];
  float a = alphap[0], bt = betap[0];
  __syncthreads();

  int l0 = lt * 512 + t, l1 = l0 + 256;
  float xr0[SC], xr1[SC];
  const float4* xp0 = (const float4*)(xn + ((size_t)nI * Ll + l0) * Cc + f * SC);
  const float4* xp1 = (const float4*)(xn + ((size_t)nI * Ll + l1) * Cc + f * SC);
#pragma unroll
  for (int q = 0; q < SC / 4; q++) {
    float4 v0 = xp0[q], v1 = xp1[q];
    xr0[4 * q] = v0.x; xr0[4 * q + 1] = v0.y; xr0[4 * q + 2] = v0.z; xr0[4 * q + 3] = v0.w;
    xr1[4 * q] = v1.x; xr1[4 * q + 1] = v1.y; xr1[4 * q + 2] = v1.z; xr1[4 * q + 3] = v1.w;
  }

  float best0 = -3.0e38f, best1 = -3.0e38f;
  int bi0 = 0, bi1 = 0;
  for (int s = 0; s < Ss; s++) {
    const float* cc = cs + s * SC;
    float p00 = 0.f, p01 = 0.f, p10 = 0.f, p11 = 0.f;
#pragma unroll
    for (int j = 0; j < SC; j += 2) {
      float cva = cc[j], cvb = cc[j + 1];
      p00 = fmaf(xr0[j], cva, p00); p01 = fmaf(xr0[j + 1], cvb, p01);
      p10 = fmaf(xr1[j], cva, p10); p11 = fmaf(xr1[j + 1], cvb, p11);
    }
    float t0 = fmaf(a, p00 + p01, bt);
    float t1 = fmaf(a, p10 + p11, bt);
    if (t0 > best0) { best0 = t0; bi0 = s; }   // strict > keeps first max (numpy rule)
    if (t1 > best1) { best1 = t1; bi1 = s; }
  }

  float mv0 = 1.f / (1.f + expf(-best0));
  float mv1 = 1.f / (1.f + expf(-best1));
  const float4* cv0 = (const float4*)(cval + (((size_t)nI * FC + f) * Ss + bi0) * SC);
  const float4* cv1 = (const float4*)(cval + (((size_t)nI * FC + f) * Ss + bi1) * SC);
  float4* d0 = (float4*)(disp + ((size_t)nI * Ll + l0) * Hh + f * SC);
  float4* d1 = (float4*)(disp + ((size_t)nI * Ll + l1) * Hh + f * SC);
#pragma unroll
  for (int q = 0; q < SC / 4; q++) {
    float4 v = cv0[q]; v.x *= mv0; v.y *= mv0; v.z *= mv0; v.w *= mv0; d0[q] = v;
    float4 w = cv1[q]; w.x *= mv1; w.y *= mv1; w.z *= mv1; w.w *= mv1; d1[q] = w;
  }
}

// ---------------------------------------------------------------------------
// Kernel D: out = dispatched @ Wm^T + bm, IN PLACE on d_out. Each block owns
// 16 disjoint rows: stages them in LDS before overwriting -> race-free.
// ---------------------------------------------------------------------------
__global__ __launch_bounds__(256) void out_kernel(
    float* __restrict__ io, const float* __restrict__ Wm,
    const float* __restrict__ bm) {
  __shared__ float xs[TM][Cc];
  int t = threadIdx.x;
  size_t row0 = (size_t)blockIdx.x * TM;

  const float4* src = (const float4*)(io + row0 * Cc);
  float4* dst = (float4*)&xs[0][0];
  for (int i = t; i < TM * Cc / 4; i += 256) dst[i] = src[i];
  __syncthreads();

  float acc[TM];
  float bb = bm[t];
#pragma unroll
  for (int r = 0; r < TM; r++) acc[r] = bb;

  const float4* w4 = (const float4*)(Wm + (size_t)t * Hh);
  for (int k4 = 0; k4 < Hh / 4; k4++) {
    float4 wv = w4[k4];
#pragma unroll
    for (int r = 0; r < TM; r++) {
      float4 xv = *(const float4*)&xs[r][k4 * 4];
      acc[r] = fmaf(xv.x, wv.x, acc[r]); acc[r] = fmaf(xv.y, wv.y, acc[r]);
      acc[r] = fmaf(xv.z, wv.z, acc[r]); acc[r] = fmaf(xv.w, wv.w, acc[r]);
    }
  }
#pragma unroll
  for (int r = 0; r < TM; r++) io[(row0 + r) * Cc + t] = acc[r];
}

// ---------------------------------------------------------------------------
extern "C" void kernel_launch(void* const* d_in, const int* in_sizes, int n_in,
                              void* d_out, int out_size, void* d_ws, size_t ws_size,
                              hipStream_t stream) {
  const float* x0      = (const float*)d_in[0];
  const float* center1 = (const float*)d_in[1];
  const float* W0      = (const float*)d_in[2];
  const float* b0      = (const float*)d_in[3];
  const float* W1      = (const float*)d_in[4];
  const float* b1      = (const float*)d_in[5];
  const float* Wm      = (const float*)d_in[6];
  const float* bm      = (const float*)d_in[7];
  const float* alpha   = (const float*)d_in[8];
  const float* beta    = (const float*)d_in[9];
  float* out = (float*)d_out;
  float* ws  = (float*)d_ws;

  float* xn   = ws;                              // N*L*C = 4,194,304 floats
  float* cpn  = xn + (size_t)Nn * Ll * Cc;       // N*FC*S*SC = 262,144 floats
  float* cval = cpn + (size_t)Nn * FC * Ss * SC; // 262,144 floats
  // total ws use: 18,874,368 bytes

  c1_kernel<<<dim3(Nn * (Ss / 16)), dim3(256), 0, stream>>>(center1, W1, b1, cpn, cval);
  x0p_kernel<<<dim3(Nn * Ll / TM), dim3(256), 0, stream>>>(x0, W0, b0, xn);
  sim_kernel<<<dim3(Nn * FC * (Ll / 512)), dim3(256), 0, stream>>>(xn, cpn, cval, alpha, beta, out);
  out_kernel<<<dim3(Nn * Ll / TM), dim3(256), 0, stream>>>(out, Wm, bm);
}

// Round 2
// 252.181 us; speedup vs baseline: 1.1007x; 1.1007x over previous
//
#include <hip/hip_runtime.h>
#include <math.h>

// Problem constants (fixed by setup_inputs)
#define Nn 4
#define Ll 4096
#define Ss 256
#define Cc 256
#define Hh 256
#define FC 8
#define SC 32     // Hh/FC

// ---------------------------------------------------------------------------
// Kernel A: c1 = center1 @ W1^T + b1 ; split into c_point (l2-normalized) and
// c_value. Layout out: cpn[n][f][s][32], cval[n][f][s][32].
// ---------------------------------------------------------------------------
__global__ __launch_bounds__(256) void c1_kernel(
    const float* __restrict__ center1, const float* __restrict__ W1,
    const float* __restrict__ b1, float* __restrict__ cpn,
    float* __restrict__ cval) {
  __shared__ float cs[16][Cc];       // 16 KB: center rows
  __shared__ float os[16][2 * Hh];   // 32 KB: outputs
  __shared__ float nr[16][FC];
  int t = threadIdx.x;
  int nI = blockIdx.x / (Ss / 16);
  int s0 = (blockIdx.x % (Ss / 16)) * 16;

  const float4* src = (const float4*)(center1 + ((size_t)nI * Ss + s0) * Cc);
  float4* dst = (float4*)&cs[0][0];
  for (int i = t; i < 16 * Cc / 4; i += 256) dst[i] = src[i];
  __syncthreads();

  float acc0[16], acc1[16];
  int c0 = t, c1 = t + 256;
  float b00 = b1[c0], b01 = b1[c1];
#pragma unroll
  for (int r = 0; r < 16; r++) { acc0[r] = b00; acc1[r] = b01; }

  const float4* w0 = (const float4*)(W1 + (size_t)c0 * Cc);
  const float4* w1 = (const float4*)(W1 + (size_t)c1 * Cc);
  for (int k4 = 0; k4 < Cc / 4; k4++) {
    float4 wa = w0[k4], wb = w1[k4];
#pragma unroll
    for (int r = 0; r < 16; r++) {
      float4 xv = *(const float4*)&cs[r][k4 * 4];
      acc0[r] = fmaf(xv.x, wa.x, acc0[r]); acc0[r] = fmaf(xv.y, wa.y, acc0[r]);
      acc0[r] = fmaf(xv.z, wa.z, acc0[r]); acc0[r] = fmaf(xv.w, wa.w, acc0[r]);
      acc1[r] = fmaf(xv.x, wb.x, acc1[r]); acc1[r] = fmaf(xv.y, wb.y, acc1[r]);
      acc1[r] = fmaf(xv.z, wb.z, acc1[r]); acc1[r] = fmaf(xv.w, wb.w, acc1[r]);
    }
  }
#pragma unroll
  for (int r = 0; r < 16; r++) { os[r][c0] = acc0[r]; os[r][c1] = acc1[r]; }
  __syncthreads();

  if (t < 128) {  // 16 rows x 8 fibers
    int r = t >> 3, f = t & 7;
    float ss = 0.f;
#pragma unroll
    for (int j = 0; j < SC; j++) { float v = os[r][f * 64 + j]; ss += v * v; }
    nr[r][f] = fmaxf(sqrtf(ss), 1e-12f);
  }
  __syncthreads();

#pragma unroll
  for (int cc = 0; cc < 2; cc++) {
    int c = t + cc * 256;
    int f = c >> 6, q = c & 63;
    for (int r = 0; r < 16; r++) {
      float v = os[r][c];
      size_t base = (((size_t)nI * FC + f) * Ss + (size_t)(s0 + r)) * SC;
      if (q < SC) cpn[base + q] = v / nr[r][f];
      else        cval[base + (q - SC)] = v;
    }
  }
}

// ---------------------------------------------------------------------------
// Shared tiled fp32 GEMM: C[M][256] = A[M][256] @ W[256][256]^T + bias.
// Block: 256 threads, tile 128 rows x 64 cols, K-tile 32.
// Per-thread 8 rows x 4 cols; XOR-swizzled LDS to kill bank conflicts.
// Per kk-step: 12 ds_read_b128 (144 cyc) vs 128 fmaf (256 cyc) -> VALU-bound.
// ---------------------------------------------------------------------------
__global__ __launch_bounds__(256) void gemm_kernel(
    const float* __restrict__ A, const float* __restrict__ W,
    const float* __restrict__ bias, float* __restrict__ C) {
  __shared__ float As[128 * 32];  // 16 KB, word (r,k) at r*32 + (k ^ (((r>>3)&3)<<2))
  __shared__ float Bs[64 * 32];   //  8 KB, word (c,k) at c*32 + (k ^ (((c>>2)&7)<<2))
  int t = threadIdx.x;
  size_t row0 = (size_t)blockIdx.x * 128;
  int cb0 = blockIdx.y * 64;

  int tc = t & 15;        // 16 col-groups x 4 cols = 64 cols
  int trg = t >> 4;       // 16 row-groups x 8 rows = 128 rows
  int r0 = trg * 8;
  int c0l = tc * 4;

  float acc[8][4];
  float4 bb = *(const float4*)&bias[cb0 + c0l];
#pragma unroll
  for (int i = 0; i < 8; i++) {
    acc[i][0] = bb.x; acc[i][1] = bb.y; acc[i][2] = bb.z; acc[i][3] = bb.w;
  }

  for (int kt = 0; kt < 8; kt++) {
    if (kt) __syncthreads();
    // stage A tile: 128 rows x 32 k
    {
      const float* ga = A + row0 * Cc + kt * 32;
#pragma unroll
      for (int it = 0; it < 4; it++) {
        int i = t + it * 256;
        int r = i >> 3, j = i & 7;
        float4 v = *(const float4*)(ga + (size_t)r * Cc + 4 * j);
        *(float4*)&As[r * 32 + ((4 * j) ^ ((((r >> 3) & 3)) << 2))] = v;
      }
      const float* gb = W + (size_t)cb0 * Cc + kt * 32;
#pragma unroll
      for (int it = 0; it < 2; it++) {
        int i = t + it * 256;
        int c = i >> 3, j = i & 7;
        float4 v = *(const float4*)(gb + (size_t)c * Cc + 4 * j);
        *(float4*)&Bs[c * 32 + ((4 * j) ^ ((((c >> 2) & 7)) << 2))] = v;
      }
    }
    __syncthreads();

    int sB = (tc & 7) << 2;
    int sA = (trg & 3) << 2;
#pragma unroll
    for (int kk = 0; kk < 8; kk++) {
      float4 Bf[4];
#pragma unroll
      for (int c = 0; c < 4; c++)
        Bf[c] = *(const float4*)&Bs[(c0l + c) * 32 + ((4 * kk) ^ sB)];
#pragma unroll
      for (int i = 0; i < 8; i++) {
        float4 Av = *(const float4*)&As[(r0 + i) * 32 + ((4 * kk) ^ sA)];
#pragma unroll
        for (int c = 0; c < 4; c++) {
          acc[i][c] = fmaf(Av.x, Bf[c].x, acc[i][c]);
          acc[i][c] = fmaf(Av.y, Bf[c].y, acc[i][c]);
          acc[i][c] = fmaf(Av.z, Bf[c].z, acc[i][c]);
          acc[i][c] = fmaf(Av.w, Bf[c].w, acc[i][c]);
        }
      }
    }
  }

#pragma unroll
  for (int i = 0; i < 8; i++) {
    float4 o; o.x = acc[i][0]; o.y = acc[i][1]; o.z = acc[i][2]; o.w = acc[i][3];
    *(float4*)&C[(row0 + r0 + i) * Cc + cb0 + c0l] = o;
  }
}

// ---------------------------------------------------------------------------
// Kernel C: per (n, f, l): normalize the 32-dim x fiber on the fly, sim
// against 256 centers via wave-uniform SCALAR loads of c_point (no LDS),
// running argmax of t = alpha*sim+beta (sigmoid monotone), gather c_value,
// scale by sigmoid(max), write dispatched IN PLACE over xn (each thread
// writes exactly the addresses it read -> race-free).
// ---------------------------------------------------------------------------
__global__ __launch_bounds__(256) void sim_kernel(
    float* __restrict__ xn, const float* __restrict__ cpn,
    const float* __restrict__ cval, const float* __restrict__ alphap,
    const float* __restrict__ betap) {
  int t = threadIdx.x;
  int lt = blockIdx.x & 15;         // 16 l-tiles of 256
  int f  = (blockIdx.x >> 4) & 7;   // fiber
  int nI = blockIdx.x >> 7;         // batch

  const float* cp = cpn + ((size_t)nI * FC + f) * Ss * SC;  // wave-uniform
  int l = lt * 256 + t;
  float* xp = xn + ((size_t)nI * Ll + l) * Cc + f * SC;

  float xr[SC];
  const float4* xp4 = (const float4*)xp;
#pragma unroll
  for (int q = 0; q < SC / 4; q++) {
    float4 v = xp4[q];
    xr[4 * q] = v.x; xr[4 * q + 1] = v.y; xr[4 * q + 2] = v.z; xr[4 * q + 3] = v.w;
  }
  float ss = 0.f;
#pragma unroll
  for (int j = 0; j < SC; j++) ss = fmaf(xr[j], xr[j], ss);
  float rin = 1.f / fmaxf(sqrtf(ss), 1e-12f);
#pragma unroll
  for (int j = 0; j < SC; j++) xr[j] *= rin;

  float a = alphap[0], bt = betap[0];
  float best = -3.0e38f;
  int bi = 0;
#pragma unroll 4
  for (int s = 0; s < Ss; s++) {
    const float* cc = cp + s * SC;  // uniform address -> s_load
    float p0 = 0.f, p1 = 0.f, p2 = 0.f, p3 = 0.f;
#pragma unroll
    for (int j = 0; j < SC; j += 4) {
      p0 = fmaf(xr[j],     cc[j],     p0);
      p1 = fmaf(xr[j + 1], cc[j + 1], p1);
      p2 = fmaf(xr[j + 2], cc[j + 2], p2);
      p3 = fmaf(xr[j + 3], cc[j + 3], p3);
    }
    float tv = fmaf(a, (p0 + p1) + (p2 + p3), bt);
    if (tv > best) { best = tv; bi = s; }  // strict > keeps first max (numpy rule)
  }

  float mv = 1.f / (1.f + expf(-best));
  const float4* cv = (const float4*)(cval + (((size_t)nI * FC + f) * Ss + bi) * SC);
  float4* d = (float4*)xp;
#pragma unroll
  for (int q = 0; q < SC / 4; q++) {
    float4 v = cv[q];
    v.x *= mv; v.y *= mv; v.z *= mv; v.w *= mv;
    d[q] = v;
  }
}

// ---------------------------------------------------------------------------
extern "C" void kernel_launch(void* const* d_in, const int* in_sizes, int n_in,
                              void* d_out, int out_size, void* d_ws, size_t ws_size,
                              hipStream_t stream) {
  const float* x0      = (const float*)d_in[0];
  const float* center1 = (const float*)d_in[1];
  const float* W0      = (const float*)d_in[2];
  const float* b0      = (const float*)d_in[3];
  const float* W1      = (const float*)d_in[4];
  const float* b1      = (const float*)d_in[5];
  const float* Wm      = (const float*)d_in[6];
  const float* bm      = (const float*)d_in[7];
  const float* alpha   = (const float*)d_in[8];
  const float* beta    = (const float*)d_in[9];
  float* out = (float*)d_out;
  float* ws  = (float*)d_ws;

  float* xn   = ws;                              // N*L*C = 4,194,304 floats (x0p, then dispatched in-place)
  float* cpn  = xn + (size_t)Nn * Ll * Cc;       // 262,144 floats
  float* cval = cpn + (size_t)Nn * FC * Ss * SC; // 262,144 floats
  // total ws use: 18,874,368 bytes

  c1_kernel<<<dim3(Nn * (Ss / 16)), dim3(256), 0, stream>>>(center1, W1, b1, cpn, cval);
  // x0p = x0 @ W0^T + b0   (raw; normalization folded into sim_kernel)
  gemm_kernel<<<dim3(Nn * Ll / 128, Cc / 64), dim3(256), 0, stream>>>(x0, W0, b0, xn);
  // sim + argmax + gather + scale, dispatched written in place over xn
  sim_kernel<<<dim3(Nn * FC * 16), dim3(256), 0, stream>>>(xn, cpn, cval, alpha, beta);
  // out = dispatched @ Wm^T + bm
  gemm_kernel<<<dim3(Nn * Ll / 128, Cc / 64), dim3(256), 0, stream>>>(xn, Wm, bm, out);
}